// Round 1
// baseline (522.840 us; speedup 1.0000x reference)
//
#include <hip/hip_runtime.h>
#include <hip/hip_bf16.h>
#include <cstdint>
#include <cstddef>

// LSTM fused pipeline for MI355X (gfx950).
// B=1024, H=1024, STEPS=4. Gate GEMMs: C[1024,4096] = [x|h](bf16,K=2048) @ [W_ih|W_hh]^T(bf16) + bias.
// m97-style 128x128 tile bf16 MFMA GEMM (global_load_lds width 16, 2-barrier loop).

typedef __bf16 bf16_t;
typedef __bf16 bf16x8 __attribute__((ext_vector_type(8)));
typedef __bf16 bf16x4 __attribute__((ext_vector_type(4)));
typedef float f32x4 __attribute__((ext_vector_type(4)));

__device__ __forceinline__ void gload_lds16(const bf16_t* g, bf16_t* l) {
    __builtin_amdgcn_global_load_lds(
        (const __attribute__((address_space(1))) void*)g,
        (__attribute__((address_space(3))) void*)l,
        16, 0, 0);
}

// C[M,N] f32 = A[M,K] bf16 @ B[N,K]^T bf16 + bias[N].
// grid = (N/128, M/128), block = 256 (4 waves, 2x2, each wave 64x64 = 4x4 frags of 16x16).
__global__ __launch_bounds__(256) void gemm_bf16_nt(
    const bf16_t* __restrict__ A, int lda,
    const bf16_t* __restrict__ B, int ldb,
    const float* __restrict__ bias,
    float* __restrict__ C, int ldc, int K)
{
    __shared__ __align__(16) bf16_t lsA[128 * 64];
    __shared__ __align__(16) bf16_t lsB[128 * 64];
    const int tid  = threadIdx.x;
    const int lane = tid & 63;
    const int wave = tid >> 6;
    const int wm = (wave >> 1) * 64;   // wave row offset in tile
    const int wn = (wave & 1) * 64;    // wave col offset in tile
    const int brow = blockIdx.y * 128;
    const int bcol = blockIdx.x * 128;

    const int srow = lane >> 3;        // 0..7 row within 8-row chunk
    const int scol = (lane & 7) * 8;   // element col within BK=64

    f32x4 acc[4][4] = {};

    for (int kt = 0; kt < K; kt += 64) {
#pragma unroll
        for (int it = 0; it < 4; ++it) {
            const int chunk = wave * 4 + it;        // 0..15, wave-uniform
            const int row = chunk * 8 + srow;       // 0..127
            // LDS dest is wave-uniform base; HW scatters lane*16 bytes. Layout: [row][k] linear.
            gload_lds16(A + (size_t)(brow + row) * lda + kt + scol, &lsA[chunk * 512]);
            gload_lds16(B + (size_t)(bcol + row) * ldb + kt + scol, &lsB[chunk * 512]);
        }
        __syncthreads();   // compiler drains vmcnt(0) before s_barrier

        const int fr = lane & 15;
#pragma unroll
        for (int kk = 0; kk < 2; ++kk) {
            const int ko = kk * 32 + (lane >> 4) * 8;
            bf16x8 af[4], bfv[4];
#pragma unroll
            for (int m = 0; m < 4; ++m)
                af[m] = *(const bf16x8*)&lsA[(wm + m * 16 + fr) * 64 + ko];
#pragma unroll
            for (int n = 0; n < 4; ++n)
                bfv[n] = *(const bf16x8*)&lsB[(wn + n * 16 + fr) * 64 + ko];
#pragma unroll
            for (int m = 0; m < 4; ++m)
#pragma unroll
                for (int n = 0; n < 4; ++n)
                    acc[m][n] = __builtin_amdgcn_mfma_f32_16x16x32_bf16(af[m], bfv[n], acc[m][n], 0, 0, 0);
        }
        __syncthreads();   // protect LDS before next stage
    }

    // C/D layout (verified m89): col = lane&15, row = (lane>>4)*4 + reg
    const int cr = (lane >> 4) * 4;
    const int cc = lane & 15;
#pragma unroll
    for (int n = 0; n < 4; ++n) {
        const int col = bcol + wn + n * 16 + cc;
        const float bv = bias[col];
#pragma unroll
        for (int m = 0; m < 4; ++m) {
            const int row0 = brow + wm + m * 16 + cr;
#pragma unroll
            for (int r = 0; r < 4; ++r)
                C[(size_t)(row0 + r) * ldc + col] = acc[m][n][r] + bv;
        }
    }
}

// ---- prep kernels ----

// Build Wcat[4096][2048] bf16 = [W_ih | W_hh] row-concat along K. 4 elems/thread.
__global__ __launch_bounds__(256) void prep_wcat(
    const float4* __restrict__ Wih, const float4* __restrict__ Whh, bf16x4* __restrict__ Wcat)
{
    const int tid = blockIdx.x * 256 + threadIdx.x;   // over 4096*256
    const int row = tid >> 8;
    const int col = tid & 255;
    const float4 a = Wih[tid];
    const float4 b = Whh[tid];
    bf16x4 va = {(bf16_t)a.x, (bf16_t)a.y, (bf16_t)a.z, (bf16_t)a.w};
    bf16x4 vb = {(bf16_t)b.x, (bf16_t)b.y, (bf16_t)b.z, (bf16_t)b.w};
    Wcat[row * 512 + col]       = va;
    Wcat[row * 512 + 256 + col] = vb;
}

// Convert W_lin [1024*1024] f32 -> bf16. 4 elems/thread.
__global__ __launch_bounds__(256) void prep_lin(
    const float4* __restrict__ W, bf16x4* __restrict__ Wb)
{
    const int tid = blockIdx.x * 256 + threadIdx.x;   // over 1024*256
    const float4 a = W[tid];
    bf16x4 v = {(bf16_t)a.x, (bf16_t)a.y, (bf16_t)a.z, (bf16_t)a.w};
    Wb[tid] = v;
}

__global__ __launch_bounds__(256) void prep_bias(
    const float* __restrict__ bih0, const float* __restrict__ bhh0,
    const float* __restrict__ bih1, const float* __restrict__ bhh1,
    float* __restrict__ bias0, float* __restrict__ bias1)
{
    const int n = blockIdx.x * 256 + threadIdx.x;     // 4096
    bias0[n] = bih0[n] + bhh0[n];
    bias1[n] = bih1[n] + bhh1[n];
}

// init: A0 = [z_bf16 | z_bf16], A1 = [z_bf16 | z_bf16], c0 = c1 = z (f32)
__global__ __launch_bounds__(256) void prep_init(
    const float* __restrict__ z, bf16_t* __restrict__ A0, bf16_t* __restrict__ A1,
    float* __restrict__ c0, float* __restrict__ c1)
{
    const int tid = blockIdx.x * 256 + threadIdx.x;   // 1M
    const int b = tid >> 10;
    const int n = tid & 1023;
    const float v = z[tid];
    const bf16_t h = (bf16_t)v;
    A0[(size_t)b * 2048 + n] = h;          // x part (z, constant)
    A0[(size_t)b * 2048 + 1024 + n] = h;   // h0 init = z
    A1[(size_t)b * 2048 + n] = h;          // x part of layer1 (h0)
    A1[(size_t)b * 2048 + 1024 + n] = h;   // h1 init = z
    c0[tid] = v;
    c1[tid] = v;
}

// LSTM cell elementwise: gates G[1024][4096] (i|f|g|o), c in f32; writes c and bf16 h
// into hA (row stride 2048) and optionally hB (row stride 2048).
__global__ __launch_bounds__(256) void lstm_cell(
    const float* __restrict__ G, float* __restrict__ c,
    bf16_t* __restrict__ hA, bf16_t* __restrict__ hB)
{
    const int tid = blockIdx.x * 256 + threadIdx.x;   // 1M
    const int b = tid >> 10;
    const int n = tid & 1023;
    const float* g = G + (size_t)b * 4096 + n;
    const float ig = g[0];
    const float fg = g[1024];
    const float gg = g[2048];
    const float og = g[3072];
    const float si = 1.f / (1.f + __expf(-ig));
    const float sf = 1.f / (1.f + __expf(-fg));
    const float so = 1.f / (1.f + __expf(-og));
    const float tg = tanhf(gg);
    const float cn = sf * c[tid] + si * tg;
    const float h  = so * tanhf(cn);
    c[tid] = cn;
    const bf16_t hb = (bf16_t)h;
    hA[(size_t)b * 2048 + n] = hb;
    if (hB) hB[(size_t)b * 2048 + n] = hb;
}

extern "C" void kernel_launch(void* const* d_in, const int* in_sizes, int n_in,
                              void* d_out, int out_size, void* d_ws, size_t ws_size,
                              hipStream_t stream)
{
    const float* z     = (const float*)d_in[0];
    const float* W_ih0 = (const float*)d_in[1];
    const float* W_hh0 = (const float*)d_in[2];
    const float* b_ih0 = (const float*)d_in[3];
    const float* b_hh0 = (const float*)d_in[4];
    const float* W_ih1 = (const float*)d_in[5];
    const float* W_hh1 = (const float*)d_in[6];
    const float* b_ih1 = (const float*)d_in[7];
    const float* b_hh1 = (const float*)d_in[8];
    const float* W_lin = (const float*)d_in[9];
    const float* b_lin = (const float*)d_in[10];
    float* out = (float*)d_out;

    char* ws = (char*)d_ws;
    bf16_t* Wcat0 = (bf16_t*)(ws);                          // 4096*2048*2 = 16MB
    bf16_t* Wcat1 = (bf16_t*)(ws + (16u << 20));            // 16MB
    bf16_t* Wlin  = (bf16_t*)(ws + (32u << 20));            // 2MB
    bf16_t* A0    = (bf16_t*)(ws + (34u << 20));            // [1024][2048] bf16 = 4MB
    bf16_t* A1    = (bf16_t*)(ws + (38u << 20));            // 4MB
    float*  G     = (float*) (ws + (42u << 20));            // [1024][4096] f32 = 16MB
    float*  c0    = (float*) (ws + (58u << 20));            // 4MB
    float*  c1    = (float*) (ws + (62u << 20));            // 4MB
    float*  bias0 = (float*) (ws + (66u << 20));            // 16KB
    float*  bias1 = (float*) (ws + (66u << 20) + 16384);    // 16KB

    prep_wcat<<<4096, 256, 0, stream>>>((const float4*)W_ih0, (const float4*)W_hh0, (bf16x4*)Wcat0);
    prep_wcat<<<4096, 256, 0, stream>>>((const float4*)W_ih1, (const float4*)W_hh1, (bf16x4*)Wcat1);
    prep_lin<<<1024, 256, 0, stream>>>((const float4*)W_lin, (bf16x4*)Wlin);
    prep_bias<<<16, 256, 0, stream>>>(b_ih0, b_hh0, b_ih1, b_hh1, bias0, bias1);
    prep_init<<<4096, 256, 0, stream>>>(z, A0, A1, c0, c1);

    for (int t = 0; t < 4; ++t) {
        // layer0: gates = [z|h0] @ Wcat0^T + bias0
        gemm_bf16_nt<<<dim3(32, 8), 256, 0, stream>>>(A0, 2048, Wcat0, 2048, bias0, G, 4096, 2048);
        // h0 -> A0 h-slot (next step) and A1 x-slot (this step)
        lstm_cell<<<4096, 256, 0, stream>>>(G, c0, A0 + 1024, A1);
        // layer1: gates = [h0|h1] @ Wcat1^T + bias1
        gemm_bf16_nt<<<dim3(32, 8), 256, 0, stream>>>(A1, 2048, Wcat1, 2048, bias1, G, 4096, 2048);
        lstm_cell<<<4096, 256, 0, stream>>>(G, c1, A1 + 1024, (bf16_t*)nullptr);
        // out[:, t, :] = h1 @ W_lin^T + b_lin
        gemm_bf16_nt<<<dim3(8, 8), 256, 0, stream>>>(A1 + 1024, 2048, Wlin, 1024, b_lin, out + t * 1024, 4096, 1024);
    }
}

// Round 2
// 345.056 us; speedup vs baseline: 1.5152x; 1.5152x over previous
//
#include <hip/hip_runtime.h>
#include <hip/hip_bf16.h>
#include <cstdint>
#include <cstddef>

// LSTM fused pipeline, round 2.
// - 2-phase double-buffered GEMM (prefetch-before-compute), 8 waves/block, 128x128 tile
// - LDS bank-conflict swizzle: linear LDS dest + pre-swizzled global source + swizzled read
// - Gz0 = z @ W_ih0^T precomputed once (z is constant across steps)
// - batched output-linear GEMM via grid.z

typedef __bf16 bf16_t;
typedef __bf16 bf16x8 __attribute__((ext_vector_type(8)));
typedef __bf16 bf16x4 __attribute__((ext_vector_type(4)));
typedef float f32x4 __attribute__((ext_vector_type(4)));

__device__ __forceinline__ void gload_lds16(const bf16_t* g, bf16_t* l) {
    __builtin_amdgcn_global_load_lds(
        (const __attribute__((address_space(1))) void*)g,
        (__attribute__((address_space(3))) void*)l,
        16, 0, 0);
}

// C[M,N] f32 = A[M,K] bf16 @ B[N,K]^T bf16 (+ bias[N] if bias).
// grid = (N/128, M/128, Z). A += z*sAz; C col block offset z*czoff.
// block = 512 (8 waves, 2x4), each wave 64x32 = 4x2 frags of 16x16.
__global__ __launch_bounds__(512) void gemm_bf16_nt(
    const bf16_t* __restrict__ A, int lda, size_t sAz,
    const bf16_t* __restrict__ B, int ldb,
    const float* __restrict__ bias,
    float* __restrict__ C, int ldc, int czoff, int K)
{
    __shared__ __align__(16) bf16_t lsA[2][128 * 64];
    __shared__ __align__(16) bf16_t lsB[2][128 * 64];
    const int tid  = threadIdx.x;
    const int lane = tid & 63;
    const int wave = tid >> 6;            // 0..7
    const int wm = (wave >> 2) * 64;      // wave row offset (2 rows of waves)
    const int wn = (wave & 3) * 32;       // wave col offset (4 cols of waves)
    const int brow = blockIdx.y * 128;
    const int bcol = blockIdx.x * 128;
    A += (size_t)blockIdx.z * sAz;

    // staging: 16 chunks of 8 rows; 2 chunks per wave per matrix.
    // LDS dest is linear (lane l -> +l*16B). Swizzle is applied by permuting the
    // GLOBAL source column slot: slot_src = (l&7) ^ (l>>3)  [rule #21].
    const int srow = lane >> 3;                       // 0..7
    const int ssw  = ((lane & 7) ^ srow) * 8;         // source col (elems) within BK=64
    const int ch0  = wave * 2;

    f32x4 acc[4][2] = {};
    const int nkt = K >> 6;

    auto stage = [&](int buf, int ktel) {
#pragma unroll
        for (int it = 0; it < 2; ++it) {
            const int ch = ch0 + it;
            const int row = ch * 8 + srow;
            gload_lds16(A + (size_t)(brow + row) * lda + ktel + ssw, &lsA[buf][ch * 512]);
            gload_lds16(B + (size_t)(bcol + row) * ldb + ktel + ssw, &lsB[buf][ch * 512]);
        }
    };

    stage(0, 0);
    __syncthreads();

    const int fr  = lane & 15;
    const int g8  = (lane >> 4) * 8;
    const int rsw = (fr & 7) * 8;         // read-side swizzle XOR (elems)

    for (int kt = 0; kt < nkt; ++kt) {
        const int buf = kt & 1;
        if (kt + 1 < nkt) stage(buf ^ 1, (kt + 1) << 6);   // prefetch BEFORE compute
#pragma unroll
        for (int kk = 0; kk < 2; ++kk) {
            const int ko = (kk * 32 + g8) ^ rsw;
            bf16x8 af[4], bfv[2];
#pragma unroll
            for (int m = 0; m < 4; ++m)
                af[m] = *(const bf16x8*)&lsA[buf][(wm + m * 16 + fr) * 64 + ko];
#pragma unroll
            for (int n = 0; n < 2; ++n)
                bfv[n] = *(const bf16x8*)&lsB[buf][(wn + n * 16 + fr) * 64 + ko];
#pragma unroll
            for (int m = 0; m < 4; ++m)
#pragma unroll
                for (int n = 0; n < 2; ++n)
                    acc[m][n] = __builtin_amdgcn_mfma_f32_16x16x32_bf16(af[m], bfv[n], acc[m][n], 0, 0, 0);
        }
        __syncthreads();   // drains this iter's prefetch vmcnt + protects LDS
    }

    // C/D layout: col = lane&15, row = (lane>>4)*4 + reg
    const int cr = (lane >> 4) * 4;
    const int cc = lane & 15;
    const size_t colz = (size_t)blockIdx.z * czoff;
#pragma unroll
    for (int n = 0; n < 2; ++n) {
        const int col = bcol + wn + n * 16 + cc;
        const float bv = bias ? bias[col] : 0.f;
#pragma unroll
        for (int m = 0; m < 4; ++m) {
            const int row0 = brow + wm + m * 16 + cr;
#pragma unroll
            for (int r = 0; r < 4; ++r)
                C[(size_t)(row0 + r) * ldc + colz + col] = acc[m][n][r] + bv;
        }
    }
}

// ---- prep kernels ----

__global__ __launch_bounds__(256) void conv_f32_bf16(
    const float4* __restrict__ in, bf16x4* __restrict__ out)
{
    const int t = blockIdx.x * 256 + threadIdx.x;
    const float4 a = in[t];
    bf16x4 v = {(bf16_t)a.x, (bf16_t)a.y, (bf16_t)a.z, (bf16_t)a.w};
    out[t] = v;
}

// Wcat[4096][2048] bf16 = [W_ih | W_hh] concat along K.
__global__ __launch_bounds__(256) void prep_wcat(
    const float4* __restrict__ Wih, const float4* __restrict__ Whh, bf16x4* __restrict__ Wcat)
{
    const int tid = blockIdx.x * 256 + threadIdx.x;   // over 4096*256
    const int row = tid >> 8;
    const int col = tid & 255;
    const float4 a = Wih[tid];
    const float4 b = Whh[tid];
    bf16x4 va = {(bf16_t)a.x, (bf16_t)a.y, (bf16_t)a.z, (bf16_t)a.w};
    bf16x4 vb = {(bf16_t)b.x, (bf16_t)b.y, (bf16_t)b.z, (bf16_t)b.w};
    Wcat[row * 512 + col]       = va;
    Wcat[row * 512 + 256 + col] = vb;
}

__global__ __launch_bounds__(256) void prep_bias(
    const float* __restrict__ bih0, const float* __restrict__ bhh0,
    const float* __restrict__ bih1, const float* __restrict__ bhh1,
    float* __restrict__ bias0, float* __restrict__ bias1)
{
    const int n = blockIdx.x * 256 + threadIdx.x;     // 4096
    bias0[n] = bih0[n] + bhh0[n];
    bias1[n] = bih1[n] + bhh1[n];
}

// write z (bf16) into P0 row slot (and +1024 slot if two0), same P1; c0=c1=z (f32)
__global__ __launch_bounds__(256) void prep_init(
    const float* __restrict__ z,
    bf16_t* __restrict__ P0, int s0, int two0,
    bf16_t* __restrict__ P1, int s1, int two1,
    float* __restrict__ c0, float* __restrict__ c1)
{
    const int tid = blockIdx.x * 256 + threadIdx.x;   // 1M
    const int b = tid >> 10;
    const int n = tid & 1023;
    const float v = z[tid];
    const bf16_t h = (bf16_t)v;
    P0[(size_t)b * s0 + n] = h;
    if (two0) P0[(size_t)b * s0 + 1024 + n] = h;
    P1[(size_t)b * s1 + n] = h;
    if (two1) P1[(size_t)b * s1 + 1024 + n] = h;
    c0[tid] = v;
    c1[tid] = v;
}

__device__ __forceinline__ float tanh_fast(float x) {
    const float t = __expf(2.f * x);
    return 1.f - 2.f / (t + 1.f);
}

// gates = GA (+GB if non-null), layout [1024][4096] f32 (i|f|g|o). 4 elems/thread.
__global__ __launch_bounds__(256) void lstm_cell(
    const float* __restrict__ GA, const float* __restrict__ GB,
    float* __restrict__ c,
    bf16_t* __restrict__ hA, int sA, bf16_t* __restrict__ hB, int sB)
{
    const int tid = blockIdx.x * 256 + threadIdx.x;   // 0..262143
    const int b  = tid >> 8;
    const int n4 = tid & 255;
    const size_t gbase = (size_t)b * 4096 + n4 * 4;
    float4 i4 = *(const float4*)(GA + gbase);
    float4 f4 = *(const float4*)(GA + gbase + 1024);
    float4 g4 = *(const float4*)(GA + gbase + 2048);
    float4 o4 = *(const float4*)(GA + gbase + 3072);
    if (GB) {
        const float4 zi = *(const float4*)(GB + gbase);
        const float4 zf = *(const float4*)(GB + gbase + 1024);
        const float4 zg = *(const float4*)(GB + gbase + 2048);
        const float4 zo = *(const float4*)(GB + gbase + 3072);
        i4.x += zi.x; i4.y += zi.y; i4.z += zi.z; i4.w += zi.w;
        f4.x += zf.x; f4.y += zf.y; f4.z += zf.z; f4.w += zf.w;
        g4.x += zg.x; g4.y += zg.y; g4.z += zg.z; g4.w += zg.w;
        o4.x += zo.x; o4.y += zo.y; o4.z += zo.z; o4.w += zo.w;
    }
    float4 c4 = *(const float4*)(c + (size_t)b * 1024 + n4 * 4);
    const float ia[4] = {i4.x, i4.y, i4.z, i4.w};
    const float fa[4] = {f4.x, f4.y, f4.z, f4.w};
    const float ga[4] = {g4.x, g4.y, g4.z, g4.w};
    const float oa[4] = {o4.x, o4.y, o4.z, o4.w};
    float ca[4] = {c4.x, c4.y, c4.z, c4.w};
    bf16x4 hb;
#pragma unroll
    for (int j = 0; j < 4; ++j) {
        const float si = 1.f / (1.f + __expf(-ia[j]));
        const float sf = 1.f / (1.f + __expf(-fa[j]));
        const float so = 1.f / (1.f + __expf(-oa[j]));
        const float tg = tanh_fast(ga[j]);
        const float cn = sf * ca[j] + si * tg;
        ca[j] = cn;
        hb[j] = (bf16_t)(so * tanh_fast(cn));
    }
    float4 co = {ca[0], ca[1], ca[2], ca[3]};
    *(float4*)(c + (size_t)b * 1024 + n4 * 4) = co;
    *(bf16x4*)(hA + (size_t)b * sA + n4 * 4) = hb;
    if (hB) *(bf16x4*)(hB + (size_t)b * sB + n4 * 4) = hb;
}

extern "C" void kernel_launch(void* const* d_in, const int* in_sizes, int n_in,
                              void* d_out, int out_size, void* d_ws, size_t ws_size,
                              hipStream_t stream)
{
    const float* z     = (const float*)d_in[0];
    const float* W_ih0 = (const float*)d_in[1];
    const float* W_hh0 = (const float*)d_in[2];
    const float* b_ih0 = (const float*)d_in[3];
    const float* b_hh0 = (const float*)d_in[4];
    const float* W_ih1 = (const float*)d_in[5];
    const float* W_hh1 = (const float*)d_in[6];
    const float* b_ih1 = (const float*)d_in[7];
    const float* b_hh1 = (const float*)d_in[8];
    const float* W_lin = (const float*)d_in[9];
    const float* b_lin = (const float*)d_in[10];
    float* out = (float*)d_out;

    char* ws = (char*)d_ws;
    const size_t MB = 1u << 20;

    if (ws_size >= 80 * MB + 32768) {
        // ---- full layout (Gz0 precompute + batched lin) ----
        bf16_t* Wih0b = (bf16_t*)(ws);               // 8MB (aliased by H1 stash after prologue)
        bf16_t* H1    = (bf16_t*)(ws);               // 4 x [1024][1024] bf16 = 8MB
        bf16_t* Whh0b = (bf16_t*)(ws + 8  * MB);     // 8MB
        bf16_t* Wcat1 = (bf16_t*)(ws + 16 * MB);     // 16MB
        bf16_t* Wlinb = (bf16_t*)(ws + 32 * MB);     // 2MB
        bf16_t* zb    = (bf16_t*)(ws + 34 * MB);     // 2MB
        bf16_t* A1    = (bf16_t*)(ws + 36 * MB);     // [1024][2048] = [h0|h1] bf16, 4MB
        float*  Gh    = (float*) (ws + 40 * MB);     // 16MB
        float*  Gz0   = (float*) (ws + 56 * MB);     // 16MB
        float*  c0    = (float*) (ws + 72 * MB);     // 4MB
        float*  c1    = (float*) (ws + 76 * MB);     // 4MB
        float*  bias0 = (float*) (ws + 80 * MB);     // 16KB
        float*  bias1 = (float*) (ws + 80 * MB + 16384);

        conv_f32_bf16<<<4096, 256, 0, stream>>>((const float4*)W_ih0, (bf16x4*)Wih0b);
        conv_f32_bf16<<<4096, 256, 0, stream>>>((const float4*)W_hh0, (bf16x4*)Whh0b);
        prep_wcat<<<4096, 256, 0, stream>>>((const float4*)W_ih1, (const float4*)W_hh1, (bf16x4*)Wcat1);
        conv_f32_bf16<<<1024, 256, 0, stream>>>((const float4*)W_lin, (bf16x4*)Wlinb);
        prep_bias<<<16, 256, 0, stream>>>(b_ih0, b_hh0, b_ih1, b_hh1, bias0, bias1);
        prep_init<<<4096, 256, 0, stream>>>(z, zb, 1024, 0, A1, 2048, 1, c0, c1);

        // Gz0 = z @ W_ih0^T + (b_ih0 + b_hh0)   [reads Wih0b before H1 aliases it]
        gemm_bf16_nt<<<dim3(32, 8, 1), 512, 0, stream>>>(zb, 1024, 0, Wih0b, 1024, bias0, Gz0, 4096, 0, 1024);

        for (int t = 0; t < 4; ++t) {
            // layer0: Gh = h0 @ W_hh0^T  (K=1024)
            gemm_bf16_nt<<<dim3(32, 8, 1), 512, 0, stream>>>(A1, 2048, 0, Whh0b, 1024, (const float*)nullptr, Gh, 4096, 0, 1024);
            // cell0: gates = Gh + Gz0 -> h0' into A1 x-slot
            lstm_cell<<<1024, 256, 0, stream>>>(Gh, Gz0, c0, A1, 2048, (bf16_t*)nullptr, 0);
            // layer1: Gh = [h0|h1] @ Wcat1^T + bias1  (K=2048)
            gemm_bf16_nt<<<dim3(32, 8, 1), 512, 0, stream>>>(A1, 2048, 0, Wcat1, 2048, bias1, Gh, 4096, 0, 2048);
            // cell1: h1' into A1 h-slot + H1 stash
            lstm_cell<<<1024, 256, 0, stream>>>(Gh, (const float*)nullptr, c1, A1 + 1024, 2048, H1 + (size_t)t * (1u << 20), 1024);
        }
        // out[:, t*1024 + n] = H1[t] @ W_lin^T + b_lin, batched over t
        gemm_bf16_nt<<<dim3(8, 8, 4), 512, 0, stream>>>(H1, 1024, (size_t)1 << 20, Wlinb, 1024, b_lin, out, 4096, 1024, 1024);
    } else {
        // ---- fallback: round-1 layout (66MB), improved GEMM ----
        bf16_t* Wcat0 = (bf16_t*)(ws);
        bf16_t* Wcat1 = (bf16_t*)(ws + 16 * MB);
        bf16_t* Wlinb = (bf16_t*)(ws + 32 * MB);
        bf16_t* A0    = (bf16_t*)(ws + 34 * MB);
        bf16_t* A1    = (bf16_t*)(ws + 38 * MB);
        float*  G     = (float*) (ws + 42 * MB);
        float*  c0    = (float*) (ws + 58 * MB);
        float*  c1    = (float*) (ws + 62 * MB);
        float*  bias0 = (float*) (ws + 66 * MB);
        float*  bias1 = (float*) (ws + 66 * MB + 16384);

        prep_wcat<<<4096, 256, 0, stream>>>((const float4*)W_ih0, (const float4*)W_hh0, (bf16x4*)Wcat0);
        prep_wcat<<<4096, 256, 0, stream>>>((const float4*)W_ih1, (const float4*)W_hh1, (bf16x4*)Wcat1);
        conv_f32_bf16<<<1024, 256, 0, stream>>>((const float4*)W_lin, (bf16x4*)Wlinb);
        prep_bias<<<16, 256, 0, stream>>>(b_ih0, b_hh0, b_ih1, b_hh1, bias0, bias1);
        prep_init<<<4096, 256, 0, stream>>>(z, A0, 2048, 1, A1, 2048, 1, c0, c1);

        for (int t = 0; t < 4; ++t) {
            gemm_bf16_nt<<<dim3(32, 8, 1), 512, 0, stream>>>(A0, 2048, 0, Wcat0, 2048, bias0, G, 4096, 0, 2048);
            lstm_cell<<<1024, 256, 0, stream>>>(G, (const float*)nullptr, c0, A0 + 1024, 2048, A1, 2048);
            gemm_bf16_nt<<<dim3(32, 8, 1), 512, 0, stream>>>(A1, 2048, 0, Wcat1, 2048, bias1, G, 4096, 0, 2048);
            lstm_cell<<<1024, 256, 0, stream>>>(G, (const float*)nullptr, c1, A1 + 1024, 2048, (bf16_t*)nullptr, 0);
            gemm_bf16_nt<<<dim3(8, 8, 1), 512, 0, stream>>>(A1 + 1024, 2048, 0, Wlinb, 1024, b_lin, out + t * 1024, 4096, 0, 1024);
        }
    }
}

// Round 3
// 225.098 us; speedup vs baseline: 2.3227x; 1.5329x over previous
//
#include <hip/hip_runtime.h>
#include <hip/hip_bf16.h>
#include <cstdint>
#include <cstddef>

// LSTM fused pipeline, round 3.
// - cell fused into GEMM epilogue via gate-interleaved layout (j = 4n + gate)
// - combo dispatches: fused1(t) [K=2048] || fused0(t+1) [K=1024] -> 512 blocks, 2/CU
// - Gz0R = z @ W_ih0R^T + bias0R precomputed once (z constant across steps)
// - 2-phase double-buffered GEMM core, LDS swizzle via pre-swizzled global source

typedef __bf16 bf16_t;
typedef __bf16 bf16x8 __attribute__((ext_vector_type(8)));
typedef __bf16 bf16x4 __attribute__((ext_vector_type(4)));
typedef float f32x4 __attribute__((ext_vector_type(4)));

__device__ __forceinline__ void gload_lds16(const bf16_t* g, bf16_t* l) {
    __builtin_amdgcn_global_load_lds(
        (const __attribute__((address_space(1))) void*)g,
        (__attribute__((address_space(3))) void*)l,
        16, 0, 0);
}

__device__ __forceinline__ float sigmoid_f(float x) {
    return 1.f / (1.f + __expf(-x));
}
__device__ __forceinline__ float tanh_fast(float x) {
    const float t = __expf(2.f * x);
    return 1.f - 2.f / (t + 1.f);
}

// Shared GEMM core: C_tile(128x128) = A[brow:+128, :K] @ B[bcol:+128, :K]^T.
// block = 512 (8 waves, 2x4), wave = 64x32 = 4x2 frags. lsA/lsB: 2 bufs x 8192 bf16 each.
__device__ __forceinline__ void gemm_core(
    const bf16_t* __restrict__ A, int lda,
    const bf16_t* __restrict__ B, int ldb,
    int K, int brow, int bcol,
    bf16_t* lsA, bf16_t* lsB, f32x4 acc[4][2])
{
    const int tid  = threadIdx.x;
    const int lane = tid & 63;
    const int wave = tid >> 6;
    const int wm = (wave >> 2) * 64;
    const int wn = (wave & 3) * 32;
    const int srow = lane >> 3;                  // 0..7
    const int ssw  = ((lane & 7) ^ srow) * 8;    // pre-swizzled source col (rule #21)
    const int ch0  = wave * 2;
    const int nkt  = K >> 6;

    auto stage = [&](int buf, int ktel) {
#pragma unroll
        for (int it = 0; it < 2; ++it) {
            const int ch = ch0 + it;
            const int row = ch * 8 + srow;
            gload_lds16(A + (size_t)(brow + row) * lda + ktel + ssw, &lsA[buf * 8192 + ch * 512]);
            gload_lds16(B + (size_t)(bcol + row) * ldb + ktel + ssw, &lsB[buf * 8192 + ch * 512]);
        }
    };

    stage(0, 0);
    __syncthreads();

    const int fr  = lane & 15;
    const int g8  = (lane >> 4) * 8;
    const int rsw = (fr & 7) * 8;                // read-side swizzle XOR (elems)

    for (int kt = 0; kt < nkt; ++kt) {
        const int buf = kt & 1;
        if (kt + 1 < nkt) stage(buf ^ 1, (kt + 1) << 6);   // prefetch BEFORE compute
#pragma unroll
        for (int kk = 0; kk < 2; ++kk) {
            const int ko = (kk * 32 + g8) ^ rsw;
            bf16x8 af[4], bfv[2];
#pragma unroll
            for (int m = 0; m < 4; ++m)
                af[m] = *(const bf16x8*)&lsA[buf * 8192 + (wm + m * 16 + fr) * 64 + ko];
#pragma unroll
            for (int n = 0; n < 2; ++n)
                bfv[n] = *(const bf16x8*)&lsB[buf * 8192 + (wn + n * 16 + fr) * 64 + ko];
#pragma unroll
            for (int m = 0; m < 4; ++m)
#pragma unroll
                for (int n = 0; n < 2; ++n)
                    acc[m][n] = __builtin_amdgcn_mfma_f32_16x16x32_bf16(af[m], bfv[n], acc[m][n], 0, 0, 0);
        }
        __syncthreads();   // drains prefetch vmcnt + protects LDS
    }
}

// ---- plain GEMM (Gz0 + output linear): C = A@B^T + bias, f32 out ----
__global__ __launch_bounds__(512) void gemm_bf16_nt(
    const bf16_t* __restrict__ A, int lda, size_t sAz,
    const bf16_t* __restrict__ B, int ldb,
    const float* __restrict__ bias,
    float* __restrict__ C, int ldc, int czoff, int K)
{
    __shared__ __align__(16) bf16_t ls[32768];
    f32x4 acc[4][2] = {};
    const int brow = blockIdx.y * 128;
    const int bcol = blockIdx.x * 128;
    gemm_core(A + (size_t)blockIdx.z * sAz, lda, B, ldb, K, brow, bcol, ls, ls + 16384, acc);

    const int lane = threadIdx.x & 63;
    const int wave = threadIdx.x >> 6;
    const int wm = (wave >> 2) * 64;
    const int wn = (wave & 3) * 32;
    const int cr = (lane >> 4) * 4;
    const int cc = lane & 15;
    const size_t colz = (size_t)blockIdx.z * czoff;
#pragma unroll
    for (int n = 0; n < 2; ++n) {
        const int col = bcol + wn + n * 16 + cc;
        const float bv = bias ? bias[col] : 0.f;
#pragma unroll
        for (int m = 0; m < 4; ++m) {
            const int row0 = brow + wm + m * 16 + cr;
#pragma unroll
            for (int r = 0; r < 4; ++r)
                C[(size_t)(row0 + r) * ldc + colz + col] = acc[m][n][r] + bv;
        }
    }
}

// ---- fused GEMM + LSTM cell (gate-interleaved layout j = 4n + gate) ----
struct FusedArgs {
    const bf16_t* A;       // [1024][lda]
    const bf16_t* B;       // [4096][K] reordered rows
    const float*  add;     // f32 [1024][4096] reordered (Gz0R) or null
    const float*  biasR;   // f32 [4096] reordered or null
    float*        c;       // f32 [1024][1024] cell state (in/out)
    bf16_t*       h1; int h1s;   // h dest 1 (stride in elems)
    bf16_t*       h2; int h2s;   // h dest 2 or null
    int K; int lda;
};

__global__ __launch_bounds__(512, 4) void fused_gemm_cell(FusedArgs fa0, FusedArgs fa1)
{
    __shared__ __align__(16) float gsm[16384];   // 64KB: staging (bf16) then gates (f32)
    const FusedArgs fa = blockIdx.z ? fa1 : fa0;
    const int brow = blockIdx.y * 128;
    const int bcol = blockIdx.x * 128;

    f32x4 acc[4][2] = {};
    bf16_t* ls = (bf16_t*)gsm;
    gemm_core(fa.A, fa.lda, fa.B, fa.K, fa.K, brow, bcol, ls, ls + 16384, acc);
    // core ends with __syncthreads() and drained vmcnt -> LDS reusable

    const int tid  = threadIdx.x;
    const int lane = tid & 63;
    const int wave = tid >> 6;
    const int wm = (wave >> 2) * 64;
    const int wn = (wave & 3) * 32;
    const int cr = (lane >> 4) * 4;
    const int cc = lane & 15;
#pragma unroll
    for (int n = 0; n < 2; ++n)
#pragma unroll
        for (int m = 0; m < 4; ++m)
#pragma unroll
            for (int r = 0; r < 4; ++r)
                gsm[(wm + m * 16 + cr + r) * 128 + wn + n * 16 + cc] = acc[m][n][r];
    __syncthreads();

    // cell: 4096 (row, n) pairs, 8 per thread; gates at [row][4nn .. 4nn+3]
#pragma unroll
    for (int p = 0; p < 8; ++p) {
        const int idx = p * 512 + tid;
        const int rl = idx >> 5;          // 0..127
        const int nn = idx & 31;          // 0..31
        float4 gv = *(const float4*)&gsm[rl * 128 + nn * 4];
        const int grow = brow + rl;
        const int j0 = bcol + nn * 4;
        if (fa.add) {
            const float4 av = *(const float4*)&fa.add[(size_t)grow * 4096 + j0];
            gv.x += av.x; gv.y += av.y; gv.z += av.z; gv.w += av.w;
        }
        if (fa.biasR) {
            const float4 bv = *(const float4*)&fa.biasR[j0];
            gv.x += bv.x; gv.y += bv.y; gv.z += bv.z; gv.w += bv.w;
        }
        const int ng = j0 >> 2;           // global n
        const size_t ci = (size_t)grow * 1024 + ng;
        const float cn = sigmoid_f(gv.y) * fa.c[ci] + sigmoid_f(gv.x) * tanh_fast(gv.z);
        const float h  = sigmoid_f(gv.w) * tanh_fast(cn);
        fa.c[ci] = cn;
        const bf16_t hb = (bf16_t)h;
        fa.h1[(size_t)grow * fa.h1s + ng] = hb;
        if (fa.h2) fa.h2[(size_t)grow * fa.h2s + ng] = hb;
    }
}

// ---- prep kernels ----

// plain f32 -> bf16 (W_lin)
__global__ __launch_bounds__(256) void conv_f32_bf16(
    const float4* __restrict__ in, bf16x4* __restrict__ out)
{
    const int t = blockIdx.x * 256 + threadIdx.x;
    const float4 a = in[t];
    bf16x4 v = {(bf16_t)a.x, (bf16_t)a.y, (bf16_t)a.z, (bf16_t)a.w};
    out[t] = v;
}

// f32 [4096][1024] -> bf16 with row reorder j=4n+g <- g*1024+n
__global__ __launch_bounds__(256) void convR_f32_bf16(
    const float4* __restrict__ in, bf16x4* __restrict__ out)
{
    const int tid = blockIdx.x * 256 + threadIdx.x;   // 4096*256
    const int j = tid >> 8;
    const int col = tid & 255;
    const int g = j & 3, n = j >> 2;
    const float4 a = in[(g * 1024 + n) * 256 + col];
    bf16x4 v = {(bf16_t)a.x, (bf16_t)a.y, (bf16_t)a.z, (bf16_t)a.w};
    out[tid] = v;
}

// WcatR[4096][2048] = [W_ih1 | W_hh1] reordered rows j=4n+g
__global__ __launch_bounds__(256) void prep_wcatR(
    const float4* __restrict__ Wih, const float4* __restrict__ Whh, bf16x4* __restrict__ Wcat)
{
    const int tid = blockIdx.x * 256 + threadIdx.x;   // 4096*256
    const int j = tid >> 8;
    const int col = tid & 255;
    const int g = j & 3, n = j >> 2;
    const int src = (g * 1024 + n) * 256 + col;
    const float4 a = Wih[src];
    const float4 b = Whh[src];
    bf16x4 va = {(bf16_t)a.x, (bf16_t)a.y, (bf16_t)a.z, (bf16_t)a.w};
    bf16x4 vb = {(bf16_t)b.x, (bf16_t)b.y, (bf16_t)b.z, (bf16_t)b.w};
    Wcat[j * 512 + col]       = va;
    Wcat[j * 512 + 256 + col] = vb;
}

__global__ __launch_bounds__(256) void prep_biasR(
    const float* __restrict__ bih0, const float* __restrict__ bhh0,
    const float* __restrict__ bih1, const float* __restrict__ bhh1,
    float* __restrict__ b0R, float* __restrict__ b1R)
{
    const int j = blockIdx.x * 256 + threadIdx.x;     // 4096
    const int g = j & 3, n = j >> 2;
    b0R[j] = bih0[g * 1024 + n] + bhh0[g * 1024 + n];
    b1R[j] = bih1[g * 1024 + n] + bhh1[g * 1024 + n];
}

// zb = bf16(z); X0 h-slot = bf16(z); c0 = c1 = z
__global__ __launch_bounds__(256) void prep_init(
    const float* __restrict__ z, bf16_t* __restrict__ zb,
    bf16_t* __restrict__ X0, float* __restrict__ c0, float* __restrict__ c1)
{
    const int tid = blockIdx.x * 256 + threadIdx.x;   // 1M
    const int b = tid >> 10;
    const int n = tid & 1023;
    const float v = z[tid];
    const bf16_t h = (bf16_t)v;
    zb[tid] = h;
    X0[(size_t)b * 2048 + 1024 + n] = h;
    c0[tid] = v;
    c1[tid] = v;
}

extern "C" void kernel_launch(void* const* d_in, const int* in_sizes, int n_in,
                              void* d_out, int out_size, void* d_ws, size_t ws_size,
                              hipStream_t stream)
{
    const float* z     = (const float*)d_in[0];
    const float* W_ih0 = (const float*)d_in[1];
    const float* W_hh0 = (const float*)d_in[2];
    const float* b_ih0 = (const float*)d_in[3];
    const float* b_hh0 = (const float*)d_in[4];
    const float* W_ih1 = (const float*)d_in[5];
    const float* W_hh1 = (const float*)d_in[6];
    const float* b_ih1 = (const float*)d_in[7];
    const float* b_hh1 = (const float*)d_in[8];
    const float* W_lin = (const float*)d_in[9];
    const float* b_lin = (const float*)d_in[10];
    float* out = (float*)d_out;

    char* ws = (char*)d_ws;
    const size_t MB = 1u << 20;
    bf16_t* WcatR1 = (bf16_t*)(ws);               // 16MB  [4096][2048]
    bf16_t* Whh0R  = (bf16_t*)(ws + 16 * MB);     // 8MB   [4096][1024]
    bf16_t* Wih0R  = (bf16_t*)(ws + 24 * MB);     // 8MB
    bf16_t* Wlinb  = (bf16_t*)(ws + 32 * MB);     // 2MB
    bf16_t* zb     = (bf16_t*)(ws + 34 * MB);     // 2MB
    bf16_t* Xbuf   = (bf16_t*)(ws + 36 * MB);     // 8MB: X[2] each [1024][2048]
    float*  Gz0R   = (float*) (ws + 44 * MB);     // 16MB  [1024][4096]
    bf16_t* stash  = (bf16_t*)(ws + 60 * MB);     // 8MB: 4 x [1024][1024]
    float*  c0     = (float*) (ws + 68 * MB);     // 4MB
    float*  c1     = (float*) (ws + 72 * MB);     // 4MB
    float*  bias0R = (float*) (ws + 76 * MB);     // 16KB
    float*  bias1R = (float*) (ws + 76 * MB + 16384);
    bf16_t* X[2] = {Xbuf, Xbuf + (size_t)(1u << 21)};

    convR_f32_bf16<<<4096, 256, 0, stream>>>((const float4*)W_ih0, (bf16x4*)Wih0R);
    convR_f32_bf16<<<4096, 256, 0, stream>>>((const float4*)W_hh0, (bf16x4*)Whh0R);
    prep_wcatR<<<4096, 256, 0, stream>>>((const float4*)W_ih1, (const float4*)W_hh1, (bf16x4*)WcatR1);
    conv_f32_bf16<<<1024, 256, 0, stream>>>((const float4*)W_lin, (bf16x4*)Wlinb);
    prep_biasR<<<16, 256, 0, stream>>>(b_ih0, b_hh0, b_ih1, b_hh1, bias0R, bias1R);
    prep_init<<<4096, 256, 0, stream>>>(z, zb, X[0], c0, c1);

    // Gz0R = z @ W_ih0R^T + bias0R (reordered cols), f32
    gemm_bf16_nt<<<dim3(32, 8, 1), 512, 0, stream>>>(zb, 1024, 0, Wih0R, 1024, bias0R, Gz0R, 4096, 0, 1024);

    // fused0(0): X[0].x = H0[1] = cell0(Gz0R + z @ Whh0R^T, c0)
    {
        FusedArgs f0;
        f0.A = zb; f0.lda = 1024; f0.B = Whh0R; f0.add = Gz0R; f0.biasR = nullptr;
        f0.c = c0; f0.h1 = X[0]; f0.h1s = 2048; f0.h2 = nullptr; f0.h2s = 0; f0.K = 1024;
        fused_gemm_cell<<<dim3(32, 8, 1), 512, 0, stream>>>(f0, f0);
    }

    for (int t = 0; t < 4; ++t) {
        const int p = t & 1;
        FusedArgs a0;   // fused1(t): K=2048, reads X[p]=[H0[t+1]|H1[t]], writes H1[t+1]
        a0.A = X[p]; a0.lda = 2048; a0.B = WcatR1; a0.add = nullptr; a0.biasR = bias1R;
        a0.c = c1; a0.h1 = stash + (size_t)t * (1u << 20); a0.h1s = 1024;
        a0.h2 = (t < 3) ? X[p ^ 1] + 1024 : nullptr; a0.h2s = 2048; a0.K = 2048;
        if (t < 3) {
            FusedArgs a1;  // fused0(t+1): K=1024, reads X[p].x=H0[t+1], writes X[p^1].x=H0[t+2]
            a1.A = X[p]; a1.lda = 2048; a1.B = Whh0R; a1.add = Gz0R; a1.biasR = nullptr;
            a1.c = c0; a1.h1 = X[p ^ 1]; a1.h1s = 2048; a1.h2 = nullptr; a1.h2s = 0; a1.K = 1024;
            fused_gemm_cell<<<dim3(32, 8, 2), 512, 0, stream>>>(a0, a1);
        } else {
            fused_gemm_cell<<<dim3(32, 8, 1), 512, 0, stream>>>(a0, a0);
        }
    }

    // out[b][t][:] = H1[t+1] @ W_lin^T + b_lin, batched over t via grid.z
    gemm_bf16_nt<<<dim3(8, 8, 4), 512, 0, stream>>>(stash, 1024, (size_t)1 << 20, Wlinb, 1024, b_lin, out, 4096, 1024, 1024);
}

// Round 4
// 224.713 us; speedup vs baseline: 2.3267x; 1.0017x over previous
//
#include <hip/hip_runtime.h>
#include <hip/hip_bf16.h>
#include <cstdint>
#include <cstddef>

// LSTM fused pipeline, round 3.
// - cell fused into GEMM epilogue via gate-interleaved layout (j = 4n + gate)
// - combo dispatches: fused1(t) [K=2048] || fused0(t+1) [K=1024] -> 512 blocks, 2/CU
// - Gz0R = z @ W_ih0R^T + bias0R precomputed once (z constant across steps)
// - 2-phase double-buffered GEMM core, LDS swizzle via pre-swizzled global source

typedef __bf16 bf16_t;
typedef __bf16 bf16x8 __attribute__((ext_vector_type(8)));
typedef __bf16 bf16x4 __attribute__((ext_vector_type(4)));
typedef float f32x4 __attribute__((ext_vector_type(4)));

__device__ __forceinline__ void gload_lds16(const bf16_t* g, bf16_t* l) {
    __builtin_amdgcn_global_load_lds(
        (const __attribute__((address_space(1))) void*)g,
        (__attribute__((address_space(3))) void*)l,
        16, 0, 0);
}

__device__ __forceinline__ float sigmoid_f(float x) {
    return 1.f / (1.f + __expf(-x));
}
__device__ __forceinline__ float tanh_fast(float x) {
    const float t = __expf(2.f * x);
    return 1.f - 2.f / (t + 1.f);
}

// Shared GEMM core: C_tile(128x128) = A[brow:+128, :K] @ B[bcol:+128, :K]^T.
// block = 512 (8 waves, 2x4), wave = 64x32 = 4x2 frags. lsA/lsB: 2 bufs x 8192 bf16 each.
__device__ __forceinline__ void gemm_core(
    const bf16_t* __restrict__ A, int lda,
    const bf16_t* __restrict__ B, int ldb,
    int K, int brow, int bcol,
    bf16_t* lsA, bf16_t* lsB, f32x4 acc[4][2])
{
    const int tid  = threadIdx.x;
    const int lane = tid & 63;
    const int wave = tid >> 6;
    const int wm = (wave >> 2) * 64;
    const int wn = (wave & 3) * 32;
    const int srow = lane >> 3;                  // 0..7
    const int ssw  = ((lane & 7) ^ srow) * 8;    // pre-swizzled source col (rule #21)
    const int ch0  = wave * 2;
    const int nkt  = K >> 6;

    auto stage = [&](int buf, int ktel) {
#pragma unroll
        for (int it = 0; it < 2; ++it) {
            const int ch = ch0 + it;
            const int row = ch * 8 + srow;
            gload_lds16(A + (size_t)(brow + row) * lda + ktel + ssw, &lsA[buf * 8192 + ch * 512]);
            gload_lds16(B + (size_t)(bcol + row) * ldb + ktel + ssw, &lsB[buf * 8192 + ch * 512]);
        }
    };

    stage(0, 0);
    __syncthreads();

    const int fr  = lane & 15;
    const int g8  = (lane >> 4) * 8;
    const int rsw = (fr & 7) * 8;                // read-side swizzle XOR (elems)

    for (int kt = 0; kt < nkt; ++kt) {
        const int buf = kt & 1;
        if (kt + 1 < nkt) stage(buf ^ 1, (kt + 1) << 6);   // prefetch BEFORE compute
#pragma unroll
        for (int kk = 0; kk < 2; ++kk) {
            const int ko = (kk * 32 + g8) ^ rsw;
            bf16x8 af[4], bfv[2];
#pragma unroll
            for (int m = 0; m < 4; ++m)
                af[m] = *(const bf16x8*)&lsA[buf * 8192 + (wm + m * 16 + fr) * 64 + ko];
#pragma unroll
            for (int n = 0; n < 2; ++n)
                bfv[n] = *(const bf16x8*)&lsB[buf * 8192 + (wn + n * 16 + fr) * 64 + ko];
#pragma unroll
            for (int m = 0; m < 4; ++m)
#pragma unroll
                for (int n = 0; n < 2; ++n)
                    acc[m][n] = __builtin_amdgcn_mfma_f32_16x16x32_bf16(af[m], bfv[n], acc[m][n], 0, 0, 0);
        }
        __syncthreads();   // drains prefetch vmcnt + protects LDS
    }
}

// ---- plain GEMM (Gz0 + output linear): C = A@B^T + bias, f32 out ----
__global__ __launch_bounds__(512) void gemm_bf16_nt(
    const bf16_t* __restrict__ A, int lda, size_t sAz,
    const bf16_t* __restrict__ B, int ldb,
    const float* __restrict__ bias,
    float* __restrict__ C, int ldc, int czoff, int K)
{
    __shared__ __align__(16) bf16_t ls[32768];
    f32x4 acc[4][2] = {};
    const int brow = blockIdx.y * 128;
    const int bcol = blockIdx.x * 128;
    gemm_core(A + (size_t)blockIdx.z * sAz, lda, B, ldb, K, brow, bcol, ls, ls + 16384, acc);

    const int lane = threadIdx.x & 63;
    const int wave = threadIdx.x >> 6;
    const int wm = (wave >> 2) * 64;
    const int wn = (wave & 3) * 32;
    const int cr = (lane >> 4) * 4;
    const int cc = lane & 15;
    const size_t colz = (size_t)blockIdx.z * czoff;
#pragma unroll
    for (int n = 0; n < 2; ++n) {
        const int col = bcol + wn + n * 16 + cc;
        const float bv = bias ? bias[col] : 0.f;
#pragma unroll
        for (int m = 0; m < 4; ++m) {
            const int row0 = brow + wm + m * 16 + cr;
#pragma unroll
            for (int r = 0; r < 4; ++r)
                C[(size_t)(row0 + r) * ldc + colz + col] = acc[m][n][r] + bv;
        }
    }
}

// ---- fused GEMM + LSTM cell (gate-interleaved layout j = 4n + gate) ----
struct FusedArgs {
    const bf16_t* A;       // [1024][lda]
    const bf16_t* B;       // [4096][K] reordered rows
    const float*  add;     // f32 [1024][4096] reordered (Gz0R) or null
    const float*  biasR;   // f32 [4096] reordered or null
    float*        c;       // f32 [1024][1024] cell state (in/out)
    bf16_t*       h1; int h1s;   // h dest 1 (stride in elems)
    bf16_t*       h2; int h2s;   // h dest 2 or null
    int K; int lda;
};

__global__ __launch_bounds__(512, 4) void fused_gemm_cell(FusedArgs fa0, FusedArgs fa1)
{
    __shared__ __align__(16) float gsm[16384];   // 64KB: staging (bf16) then gates (f32)
    const FusedArgs fa = blockIdx.z ? fa1 : fa0;
    const int brow = blockIdx.y * 128;
    const int bcol = blockIdx.x * 128;

    f32x4 acc[4][2] = {};
    bf16_t* ls = (bf16_t*)gsm;
    gemm_core(fa.A, fa.lda, fa.B, fa.K, fa.K, brow, bcol, ls, ls + 16384, acc);
    // core ends with __syncthreads() and drained vmcnt -> LDS reusable

    const int tid  = threadIdx.x;
    const int lane = tid & 63;
    const int wave = tid >> 6;
    const int wm = (wave >> 2) * 64;
    const int wn = (wave & 3) * 32;
    const int cr = (lane >> 4) * 4;
    const int cc = lane & 15;
#pragma unroll
    for (int n = 0; n < 2; ++n)
#pragma unroll
        for (int m = 0; m < 4; ++m)
#pragma unroll
            for (int r = 0; r < 4; ++r)
                gsm[(wm + m * 16 + cr + r) * 128 + wn + n * 16 + cc] = acc[m][n][r];
    __syncthreads();

    // cell: 4096 (row, n) pairs, 8 per thread; gates at [row][4nn .. 4nn+3]
#pragma unroll
    for (int p = 0; p < 8; ++p) {
        const int idx = p * 512 + tid;
        const int rl = idx >> 5;          // 0..127
        const int nn = idx & 31;          // 0..31
        float4 gv = *(const float4*)&gsm[rl * 128 + nn * 4];
        const int grow = brow + rl;
        const int j0 = bcol + nn * 4;
        if (fa.add) {
            const float4 av = *(const float4*)&fa.add[(size_t)grow * 4096 + j0];
            gv.x += av.x; gv.y += av.y; gv.z += av.z; gv.w += av.w;
        }
        if (fa.biasR) {
            const float4 bv = *(const float4*)&fa.biasR[j0];
            gv.x += bv.x; gv.y += bv.y; gv.z += bv.z; gv.w += bv.w;
        }
        const int ng = j0 >> 2;           // global n
        const size_t ci = (size_t)grow * 1024 + ng;
        const float cn = sigmoid_f(gv.y) * fa.c[ci] + sigmoid_f(gv.x) * tanh_fast(gv.z);
        const float h  = sigmoid_f(gv.w) * tanh_fast(cn);
        fa.c[ci] = cn;
        const bf16_t hb = (bf16_t)h;
        fa.h1[(size_t)grow * fa.h1s + ng] = hb;
        if (fa.h2) fa.h2[(size_t)grow * fa.h2s + ng] = hb;
    }
}

// ---- prep kernels ----

// plain f32 -> bf16 (W_lin)
__global__ __launch_bounds__(256) void conv_f32_bf16(
    const float4* __restrict__ in, bf16x4* __restrict__ out)
{
    const int t = blockIdx.x * 256 + threadIdx.x;
    const float4 a = in[t];
    bf16x4 v = {(bf16_t)a.x, (bf16_t)a.y, (bf16_t)a.z, (bf16_t)a.w};
    out[t] = v;
}

// f32 [4096][1024] -> bf16 with row reorder j=4n+g <- g*1024+n
__global__ __launch_bounds__(256) void convR_f32_bf16(
    const float4* __restrict__ in, bf16x4* __restrict__ out)
{
    const int tid = blockIdx.x * 256 + threadIdx.x;   // 4096*256
    const int j = tid >> 8;
    const int col = tid & 255;
    const int g = j & 3, n = j >> 2;
    const float4 a = in[(g * 1024 + n) * 256 + col];
    bf16x4 v = {(bf16_t)a.x, (bf16_t)a.y, (bf16_t)a.z, (bf16_t)a.w};
    out[tid] = v;
}

// WcatR[4096][2048] = [W_ih1 | W_hh1] reordered rows j=4n+g
__global__ __launch_bounds__(256) void prep_wcatR(
    const float4* __restrict__ Wih, const float4* __restrict__ Whh, bf16x4* __restrict__ Wcat)
{
    const int tid = blockIdx.x * 256 + threadIdx.x;   // 4096*256
    const int j = tid >> 8;
    const int col = tid & 255;
    const int g = j & 3, n = j >> 2;
    const int src = (g * 1024 + n) * 256 + col;
    const float4 a = Wih[src];
    const float4 b = Whh[src];
    bf16x4 va = {(bf16_t)a.x, (bf16_t)a.y, (bf16_t)a.z, (bf16_t)a.w};
    bf16x4 vb = {(bf16_t)b.x, (bf16_t)b.y, (bf16_t)b.z, (bf16_t)b.w};
    Wcat[j * 512 + col]       = va;
    Wcat[j * 512 + 256 + col] = vb;
}

__global__ __launch_bounds__(256) void prep_biasR(
    const float* __restrict__ bih0, const float* __restrict__ bhh0,
    const float* __restrict__ bih1, const float* __restrict__ bhh1,
    float* __restrict__ b0R, float* __restrict__ b1R)
{
    const int j = blockIdx.x * 256 + threadIdx.x;     // 4096
    const int g = j & 3, n = j >> 2;
    b0R[j] = bih0[g * 1024 + n] + bhh0[g * 1024 + n];
    b1R[j] = bih1[g * 1024 + n] + bhh1[g * 1024 + n];
}

// zb = bf16(z); X0 h-slot = bf16(z); c0 = c1 = z
__global__ __launch_bounds__(256) void prep_init(
    const float* __restrict__ z, bf16_t* __restrict__ zb,
    bf16_t* __restrict__ X0, float* __restrict__ c0, float* __restrict__ c1)
{
    const int tid = blockIdx.x * 256 + threadIdx.x;   // 1M
    const int b = tid >> 10;
    const int n = tid & 1023;
    const float v = z[tid];
    const bf16_t h = (bf16_t)v;
    zb[tid] = h;
    X0[(size_t)b * 2048 + 1024 + n] = h;
    c0[tid] = v;
    c1[tid] = v;
}

extern "C" void kernel_launch(void* const* d_in, const int* in_sizes, int n_in,
                              void* d_out, int out_size, void* d_ws, size_t ws_size,
                              hipStream_t stream)
{
    const float* z     = (const float*)d_in[0];
    const float* W_ih0 = (const float*)d_in[1];
    const float* W_hh0 = (const float*)d_in[2];
    const float* b_ih0 = (const float*)d_in[3];
    const float* b_hh0 = (const float*)d_in[4];
    const float* W_ih1 = (const float*)d_in[5];
    const float* W_hh1 = (const float*)d_in[6];
    const float* b_ih1 = (const float*)d_in[7];
    const float* b_hh1 = (const float*)d_in[8];
    const float* W_lin = (const float*)d_in[9];
    const float* b_lin = (const float*)d_in[10];
    float* out = (float*)d_out;

    char* ws = (char*)d_ws;
    const size_t MB = 1u << 20;
    bf16_t* WcatR1 = (bf16_t*)(ws);               // 16MB  [4096][2048]
    bf16_t* Whh0R  = (bf16_t*)(ws + 16 * MB);     // 8MB   [4096][1024]
    bf16_t* Wih0R  = (bf16_t*)(ws + 24 * MB);     // 8MB
    bf16_t* Wlinb  = (bf16_t*)(ws + 32 * MB);     // 2MB
    bf16_t* zb     = (bf16_t*)(ws + 34 * MB);     // 2MB
    bf16_t* Xbuf   = (bf16_t*)(ws + 36 * MB);     // 8MB: X[2] each [1024][2048]
    float*  Gz0R   = (float*) (ws + 44 * MB);     // 16MB  [1024][4096]
    bf16_t* stash  = (bf16_t*)(ws + 60 * MB);     // 8MB: 4 x [1024][1024]
    float*  c0     = (float*) (ws + 68 * MB);     // 4MB
    float*  c1     = (float*) (ws + 72 * MB);     // 4MB
    float*  bias0R = (float*) (ws + 76 * MB);     // 16KB
    float*  bias1R = (float*) (ws + 76 * MB + 16384);
    bf16_t* X[2] = {Xbuf, Xbuf + (size_t)(1u << 21)};

    convR_f32_bf16<<<4096, 256, 0, stream>>>((const float4*)W_ih0, (bf16x4*)Wih0R);
    convR_f32_bf16<<<4096, 256, 0, stream>>>((const float4*)W_hh0, (bf16x4*)Whh0R);
    prep_wcatR<<<4096, 256, 0, stream>>>((const float4*)W_ih1, (const float4*)W_hh1, (bf16x4*)WcatR1);
    conv_f32_bf16<<<1024, 256, 0, stream>>>((const float4*)W_lin, (bf16x4*)Wlinb);
    prep_biasR<<<16, 256, 0, stream>>>(b_ih0, b_hh0, b_ih1, b_hh1, bias0R, bias1R);
    prep_init<<<4096, 256, 0, stream>>>(z, zb, X[0], c0, c1);

    // Gz0R = z @ W_ih0R^T + bias0R (reordered cols), f32
    gemm_bf16_nt<<<dim3(32, 8, 1), 512, 0, stream>>>(zb, 1024, 0, Wih0R, 1024, bias0R, Gz0R, 4096, 0, 1024);

    // fused0(0): X[0].x = H0[1] = cell0(Gz0R + z @ Whh0R^T, c0)
    {
        FusedArgs f0;
        f0.A = zb; f0.lda = 1024; f0.B = Whh0R; f0.add = Gz0R; f0.biasR = nullptr;
        f0.c = c0; f0.h1 = X[0]; f0.h1s = 2048; f0.h2 = nullptr; f0.h2s = 0; f0.K = 1024;
        fused_gemm_cell<<<dim3(32, 8, 1), 512, 0, stream>>>(f0, f0);
    }

    for (int t = 0; t < 4; ++t) {
        const int p = t & 1;
        FusedArgs a0;   // fused1(t): K=2048, reads X[p]=[H0[t+1]|H1[t]], writes H1[t+1]
        a0.A = X[p]; a0.lda = 2048; a0.B = WcatR1; a0.add = nullptr; a0.biasR = bias1R;
        a0.c = c1; a0.h1 = stash + (size_t)t * (1u << 20); a0.h1s = 1024;
        a0.h2 = (t < 3) ? X[p ^ 1] + 1024 : nullptr; a0.h2s = 2048; a0.K = 2048;
        if (t < 3) {
            FusedArgs a1;  // fused0(t+1): K=1024, reads X[p].x=H0[t+1], writes X[p^1].x=H0[t+2]
            a1.A = X[p]; a1.lda = 2048; a1.B = Whh0R; a1.add = Gz0R; a1.biasR = nullptr;
            a1.c = c0; a1.h1 = X[p ^ 1]; a1.h1s = 2048; a1.h2 = nullptr; a1.h2s = 0; a1.K = 1024;
            fused_gemm_cell<<<dim3(32, 8, 2), 512, 0, stream>>>(a0, a1);
        } else {
            fused_gemm_cell<<<dim3(32, 8, 1), 512, 0, stream>>>(a0, a0);
        }
    }

    // out[b][t][:] = H1[t+1] @ W_lin^T + b_lin, batched over t via grid.z
    gemm_bf16_nt<<<dim3(8, 8, 4), 512, 0, stream>>>(stash, 1024, (size_t)1 << 20, Wlinb, 1024, b_lin, out, 4096, 1024, 1024);
}